// Round 1
// baseline (916.018 us; speedup 1.0000x reference)
//
#include <hip/hip_runtime.h>
#include <hip/hip_bf16.h>

// Problem constants (from reference)
constexpr int NN   = 10000;  // N_NODES
constexpr int DMAX = 128;    // D_MAX
constexpr int TB   = 128;    // threads per block = B*F = 2*64 (b,f) pairs
constexpr int ROWS = 128;    // B*F rows of x

// ---------------------------------------------------------------------------
// Kernel 1: transpose x (128, 10000) -> xT (10000, 128) so each node's 128
// (b,f) values are one contiguous 512B line (coalesced neighbor gathers).
// ---------------------------------------------------------------------------
__global__ __launch_bounds__(256) void transpose_kernel(
    const float* __restrict__ x, float* __restrict__ xT)
{
    __shared__ float tile[32][33];
    const int n0 = blockIdx.x * 32;
    const int r0 = blockIdx.y * 32;
    const int tx = threadIdx.x;   // 0..31
    const int ty = threadIdx.y;   // 0..7
    #pragma unroll
    for (int i = 0; i < 32; i += 8) {
        const int r = r0 + ty + i;
        const int n = n0 + tx;
        if (n < NN) tile[ty + i][tx] = x[(size_t)r * NN + n];
    }
    __syncthreads();
    #pragma unroll
    for (int i = 0; i < 32; i += 8) {
        const int n = n0 + ty + i;
        const int r = r0 + tx;
        if (n < NN) xT[(size_t)n * ROWS + r] = tile[tx][ty + i];
    }
}

// ---------------------------------------------------------------------------
// Kernel 2: per node, for each hop k: stage vals[j][t] = xT[idx[j]][t] in LDS,
// exact median per thread via chunked counting selection, then combine.
// ---------------------------------------------------------------------------
__global__ __launch_bounds__(128, 1) void median_combine(
    const float* __restrict__ xT, const float* __restrict__ w,
    const int* __restrict__ nidx, const int* __restrict__ nlen,
    float* __restrict__ out)
{
    __shared__ float vals[DMAX * TB];   // 64 KB, layout [j][t]
    const int n = blockIdx.x;
    const int t = threadIdx.x;
    const float INF = __builtin_inff();

    float med[2];

    #pragma unroll
    for (int k = 0; k < 2; ++k) {
        const int ln  = nlen[k * NN + n];          // uniform across block
        const int lnp = (ln + 7) & ~7;             // pad rows to multiple of 8
        const int mid = (ln - 1) >> 1;
        const int* idxp = nidx + ((size_t)k * NN + n) * DMAX;

        // ---- stage: 4 neighbor rows per iteration, float4 per lane-group ----
        {
            const int jr = t >> 5;          // 0..3: which of 4 rows
            const int c4 = (t & 31) * 4;    // float4 column
            for (int j0 = 0; j0 < lnp; j0 += 4) {
                const int j = j0 + jr;
                if (j < ln) {
                    const int nb = idxp[j];
                    const float4 v =
                        *reinterpret_cast<const float4*>(xT + (size_t)nb * ROWS + c4);
                    *reinterpret_cast<float4*>(&vals[j * TB + c4]) = v;
                } else if (j < lnp) {
                    *reinterpret_cast<float4*>(&vals[j * TB + c4]) =
                        make_float4(INF, INF, INF, INF);
                }
            }
        }
        __syncthreads();

        // ---- counting selection: 16 candidates/chunk, stream values ----
        float m = 0.f;
        int found = 0;
        for (int c0 = 0; c0 < ln; c0 += 16) {
            float cand[16];
            int   cnt[16];
            #pragma unroll
            for (int c = 0; c < 16; ++c) {
                const int i = c0 + c;
                cand[c] = (i < ln) ? vals[i * TB + t] : INF;
                cnt[c]  = 0;
            }
            for (int j0 = 0; j0 < lnp; j0 += 8) {
                #pragma unroll
                for (int jj = 0; jj < 8; ++jj) {
                    const float vj = vals[(j0 + jj) * TB + t];
                    #pragma unroll
                    for (int c = 0; c < 16; ++c)
                        cnt[c] += (vj < cand[c]) ? 1 : 0;   // INF pads add 0
                }
            }
            #pragma unroll
            for (int c = 0; c < 16; ++c) {
                if ((c0 + c) < ln && cnt[c] == mid) { m = cand[c]; found = 1; }
            }
        }

        // ---- rare exact-duplicate ties: no element has strict-rank == mid ----
        if (__any(!found)) {
            if (!found) {
                for (int i = 0; i < ln; ++i) {
                    const float ci = vals[i * TB + t];
                    int lt = 0, eq = 0;
                    for (int j = 0; j < ln; ++j) {
                        const float vj = vals[j * TB + t];
                        lt += (vj < ci) ? 1 : 0;
                        eq += (vj == ci) ? 1 : 0;
                    }
                    if (lt <= mid && mid < lt + eq) m = ci;
                }
            }
        }
        med[k] = m;
        __syncthreads();   // before restaging next hop
    }

    // ---- combine: out = w0*x + w1*med1 + w2*med2 ----
    const float xv = xT[(size_t)n * ROWS + t];
    out[(size_t)t * NN + n] = w[0] * xv + w[1] * med[0] + w[2] * med[1];
}

extern "C" void kernel_launch(void* const* d_in, const int* in_sizes, int n_in,
                              void* d_out, int out_size, void* d_ws, size_t ws_size,
                              hipStream_t stream) {
    const float* x    = (const float*)d_in[0];   // (2,64,10000) f32
    const float* w    = (const float*)d_in[1];   // (1,3) f32
    const int*   nidx = (const int*)d_in[2];     // (2,10000,128) i32
    const int*   nlen = (const int*)d_in[3];     // (2,10000) i32
    float* out = (float*)d_out;                  // (2,64,10000) f32
    float* xT  = (float*)d_ws;                   // 10000*128 f32 = 5.12 MB scratch

    dim3 tb(32, 8);
    dim3 tg((NN + 31) / 32, ROWS / 32);
    transpose_kernel<<<tg, tb, 0, stream>>>(x, xT);
    median_combine<<<NN, TB, 0, stream>>>(xT, w, nidx, nlen, out);
}

// Round 2
// 452.638 us; speedup vs baseline: 2.0237x; 2.0237x over previous
//
#include <hip/hip_runtime.h>
#include <hip/hip_bf16.h>

// Problem constants (from reference)
constexpr int NN   = 10000;  // N_NODES
constexpr int DMAX = 128;    // D_MAX
constexpr int ROWS = 128;    // B*F rows of x
constexpr int COLS = 128;    // B*F columns per node

// ---------------------------------------------------------------------------
// Kernel 1: transpose x (128, 10000) -> xT (10000, 128): each node's 128
// (b,f) values become one contiguous 512B line (coalesced neighbor gathers).
// ---------------------------------------------------------------------------
__global__ __launch_bounds__(256) void transpose_kernel(
    const float* __restrict__ x, float* __restrict__ xT)
{
    __shared__ float tile[32][33];
    const int n0 = blockIdx.x * 32;
    const int r0 = blockIdx.y * 32;
    const int tx = threadIdx.x;   // 0..31
    const int ty = threadIdx.y;   // 0..7
    #pragma unroll
    for (int i = 0; i < 32; i += 8) {
        const int r = r0 + ty + i;
        const int n = n0 + tx;
        if (n < NN) tile[ty + i][tx] = x[(size_t)r * NN + n];
    }
    __syncthreads();
    #pragma unroll
    for (int i = 0; i < 32; i += 8) {
        const int n = n0 + ty + i;
        const int r = r0 + tx;
        if (n < NN) xT[(size_t)n * ROWS + r] = tile[tx][ty + i];
    }
}

// ---------------------------------------------------------------------------
// Kernel 2: one block (256 thr) per node. Stage vals[j][col] in LDS, then
// exact median per column via bracketed quickselect with data-snapping:
//   per pass: c = #{v<=m}, mx = max{v<=m}, mn = min{v>m}
//   c==mid+1 -> x=mx ; c==mid -> x=mn ; lo>=hi -> x=lo
//   c>mid+1 -> hi=mx ; c<mid -> lo=mn   (bracket strictly shrinks, dup-safe)
// Pivot: Newton on empirical CDF (data ~ N(0,1)), clamped to bracket.
// Lanes l and l^32 split the j-range of one column; combine via shfl_xor(32).
// ---------------------------------------------------------------------------
__global__ __launch_bounds__(256, 2) void median_combine(
    const float* __restrict__ xT, const float* __restrict__ w,
    const int* __restrict__ nidx, const int* __restrict__ nlen,
    float* __restrict__ out)
{
    __shared__ float vals[DMAX * COLS];   // 64 KB, layout [j][col]
    const int n    = blockIdx.x;
    const int t    = threadIdx.x;         // 0..255
    const int wave = t >> 6;              // 0..3
    const int lane = t & 63;
    const int col  = (wave << 5) | (lane & 31);   // 0..127 (= b*64+f)
    const int half = lane >> 5;           // 0 or 1: which j-half I scan

    float medk[2];

    #pragma unroll
    for (int k = 0; k < 2; ++k) {
        const int ln  = nlen[k * NN + n];          // block-uniform
        const int lnp = (ln + 7) & ~7;             // pad rows to multiple of 8
        const int mid = (ln - 1) >> 1;
        const int* idxp = nidx + ((size_t)k * NN + n) * DMAX;

        // ---- stage: 8 neighbor rows per iter, float4 per lane-group ----
        {
            const int jr = t >> 5;         // 0..7: row within group of 8
            const int c4 = (t & 31) << 2;  // float4 column
            for (int j0 = 0; j0 < lnp; j0 += 8) {
                const int j = j0 + jr;
                if (j < ln) {
                    const int nb = idxp[j];
                    const float4 v =
                        *reinterpret_cast<const float4*>(xT + (size_t)nb * ROWS + c4);
                    *reinterpret_cast<float4*>(&vals[j * COLS + c4]) = v;
                } else if (j < lnp) {
                    *reinterpret_cast<float4*>(&vals[j * COLS + c4]) =
                        make_float4(1e30f, 1e30f, 1e30f, 1e30f);  // pads never count
                }
            }
        }
        __syncthreads();

        const int   H    = lnp >> 1;               // my half-length (mult of 4)
        const float invd = 1.0f / (0.4f * (float)ln);
        const float* vp  = &vals[(half * H) * COLS + col];

        float lo = -64.f, hi = 64.f, m = 0.f, x = 0.f;  // |data| < 10 << 64
        bool active = true;

        while (__ballot(active) != 0ull) {
            if (active) {
                if (lo >= hi) {            // bracket collapsed: answer = lo
                    x = lo; active = false;
                } else {
                    // ---- pass over my half: 4 independent accumulator sets ----
                    int   c0 = 0, c1 = 0, c2 = 0, c3 = 0;
                    float mx0 = -1e30f, mx1 = -1e30f, mx2 = -1e30f, mx3 = -1e30f;
                    float mn0 =  1e30f, mn1 =  1e30f, mn2 =  1e30f, mn3 =  1e30f;
                    for (int j = 0; j < H; j += 4) {
                        const float v0 = vp[(j + 0) * COLS];
                        const float v1 = vp[(j + 1) * COLS];
                        const float v2 = vp[(j + 2) * COLS];
                        const float v3 = vp[(j + 3) * COLS];
                        const bool l0 = v0 <= m, l1 = v1 <= m,
                                   l2 = v2 <= m, l3 = v3 <= m;
                        c0 += l0; mx0 = l0 ? fmaxf(mx0, v0) : mx0; mn0 = l0 ? mn0 : fminf(mn0, v0);
                        c1 += l1; mx1 = l1 ? fmaxf(mx1, v1) : mx1; mn1 = l1 ? mn1 : fminf(mn1, v1);
                        c2 += l2; mx2 = l2 ? fmaxf(mx2, v2) : mx2; mn2 = l2 ? mn2 : fminf(mn2, v2);
                        c3 += l3; mx3 = l3 ? fmaxf(mx3, v3) : mx3; mn3 = l3 ? mn3 : fminf(mn3, v3);
                    }
                    int   c  = (c0 + c1) + (c2 + c3);
                    float mx = fmaxf(fmaxf(mx0, mx1), fmaxf(mx2, mx3));
                    float mn = fminf(fminf(mn0, mn1), fminf(mn2, mn3));
                    // combine the two j-halves (partner lane has identical state)
                    c  += __shfl_xor(c, 32);
                    mx  = fmaxf(mx, __shfl_xor(mx, 32));
                    mn  = fminf(mn, __shfl_xor(mn, 32));

                    if (c == mid + 1)      { x = mx; active = false; }
                    else if (c == mid)     { x = mn; active = false; }
                    else {
                        if (c > mid + 1) hi = mx;   // snap: mx <= m < hi, strict shrink
                        else             lo = mn;   // snap: mn >  m >= lo, strict shrink
                        // Newton pivot on empirical CDF, clamped into bracket
                        float mN = m + ((float)(mid - c) + 0.5f) * invd;
                        if (!(mN > lo && mN < hi)) mN = 0.5f * (lo + hi);
                        if (mN >= hi) mN = lo;      // keep invariant m in [lo, hi)
                        m = mN;
                    }
                }
            }
        }
        medk[k] = x;
        __syncthreads();   // all waves done before restaging next hop
    }

    // ---- combine: out = w0*x + w1*med1 + w2*med2 (one writer per column) ----
    if (half == 0) {
        const float xv = xT[(size_t)n * ROWS + col];
        out[(size_t)col * NN + n] = w[0] * xv + w[1] * medk[0] + w[2] * medk[1];
    }
}

extern "C" void kernel_launch(void* const* d_in, const int* in_sizes, int n_in,
                              void* d_out, int out_size, void* d_ws, size_t ws_size,
                              hipStream_t stream) {
    const float* x    = (const float*)d_in[0];   // (2,64,10000) f32
    const float* w    = (const float*)d_in[1];   // (1,3) f32
    const int*   nidx = (const int*)d_in[2];     // (2,10000,128) i32
    const int*   nlen = (const int*)d_in[3];     // (2,10000) i32
    float* out = (float*)d_out;                  // (2,64,10000) f32
    float* xT  = (float*)d_ws;                   // 10000*128 f32 = 5.12 MB scratch

    dim3 tb(32, 8);
    dim3 tg((NN + 31) / 32, ROWS / 32);
    transpose_kernel<<<tg, tb, 0, stream>>>(x, xT);
    median_combine<<<NN, 256, 0, stream>>>(xT, w, nidx, nlen, out);
}